// Round 1
// baseline (127.379 us; speedup 1.0000x reference)
//
#include <hip/hip_runtime.h>
#include <math.h>

#define N_PTS 16384
#define KNN   16
#define NCLS  20
#define BND_W 1.0f

#define BLK   256            // threads per block
#define CPT   4              // centers per thread
#define CPB   (BLK * CPT)    // centers per block = 1024
#define PB    (N_PTS / CPB)  // point blocks = 16
#define CHUNK 512            // candidates per chunk
#define CC    (N_PTS / CHUNK) // candidate chunks = 32

// identical distance expression used in both passes (same rounding)
__device__ __forceinline__ float dist2(float cx, float cy, float cz,
                                       float vx, float vy, float vz) {
    float dx = cx - vx, dy = cy - vy, dz = cz - vz;
    return fmaf(dx, dx, fmaf(dy, dy, dz * dz));
}

// Pass 1: per-center min distance to a valid, differently-labeled point.
__global__ __launch_bounds__(BLK) void k_dmin(const float* __restrict__ coord,
                                              const int* __restrict__ seg,
                                              unsigned int* __restrict__ dmin_bits) {
    __shared__ float4 lds[CHUNK];
    const int pb = blockIdx.x;  // point block
    const int cc = blockIdx.y;  // candidate chunk
    const int tid = threadIdx.x;

    for (int t = tid; t < CHUNK; t += BLK) {
        int j = cc * CHUNK + t;
        float4 v;
        v.x = coord[3 * j + 0];
        v.y = coord[3 * j + 1];
        v.z = coord[3 * j + 2];
        v.w = __int_as_float(seg[j]);
        lds[t] = v;
    }
    __syncthreads();

    float cx[CPT], cy[CPT], cz[CPT], dmin[CPT];
    int cs[CPT];
    const int base = pb * CPB;
#pragma unroll
    for (int c = 0; c < CPT; c++) {
        int i = base + c * BLK + tid;
        cx[c] = coord[3 * i + 0];
        cy[c] = coord[3 * i + 1];
        cz[c] = coord[3 * i + 2];
        cs[c] = seg[i];
        dmin[c] = 3.0e38f;
    }

    for (int t = 0; t < CHUNK; t++) {
        float4 v = lds[t];
        int vs = __float_as_int(v.w);
#pragma unroll
        for (int c = 0; c < CPT; c++) {
            float d = dist2(cx[c], cy[c], cz[c], v.x, v.y, v.z);
            bool diff = (vs != -1) && (vs != cs[c]);
            float dsel = diff ? d : 3.0e38f;
            dmin[c] = fminf(dmin[c], dsel);
        }
    }

#pragma unroll
    for (int c = 0; c < CPT; c++) {
        int i = base + c * BLK + tid;
        atomicMin(&dmin_bits[i], __float_as_uint(dmin[c]));
    }
}

// Pass 2: count points strictly closer than dmin_diff (self gets counted once; subtract later).
__global__ __launch_bounds__(BLK) void k_count(const float* __restrict__ coord,
                                               const unsigned int* __restrict__ dmin_bits,
                                               int* __restrict__ cnt) {
    __shared__ float4 lds[CHUNK];
    const int pb = blockIdx.x;
    const int cc = blockIdx.y;
    const int tid = threadIdx.x;

    for (int t = tid; t < CHUNK; t += BLK) {
        int j = cc * CHUNK + t;
        float4 v;
        v.x = coord[3 * j + 0];
        v.y = coord[3 * j + 1];
        v.z = coord[3 * j + 2];
        v.w = 0.0f;
        lds[t] = v;
    }
    __syncthreads();

    float cx[CPT], cy[CPT], cz[CPT], thr[CPT];
    int lcnt[CPT];
    const int base = pb * CPB;
#pragma unroll
    for (int c = 0; c < CPT; c++) {
        int i = base + c * BLK + tid;
        cx[c] = coord[3 * i + 0];
        cy[c] = coord[3 * i + 1];
        cz[c] = coord[3 * i + 2];
        thr[c] = __uint_as_float(dmin_bits[i]);
        lcnt[c] = 0;
    }

    for (int t = 0; t < CHUNK; t++) {
        float4 v = lds[t];
#pragma unroll
        for (int c = 0; c < CPT; c++) {
            float d = dist2(cx[c], cy[c], cz[c], v.x, v.y, v.z);
            lcnt[c] += (d < thr[c]) ? 1 : 0;
        }
    }

#pragma unroll
    for (int c = 0; c < CPT; c++) {
        int i = base + c * BLK + tid;
        atomicAdd(&cnt[i], lcnt[c]);
    }
}

__device__ __forceinline__ float waveReduceSum(float v) {
#pragma unroll
    for (int off = 32; off > 0; off >>= 1) v += __shfl_down(v, off, 64);
    return v;
}

// Pass 3: cross-entropy + masked accumulation.
// accum: [0]=sum_main, [1]=cnt_main, [2]=sum_bnd, [3]=cnt_bnd
__global__ __launch_bounds__(BLK) void k_ce(const float* __restrict__ logits,
                                            const int* __restrict__ seg,
                                            const int* __restrict__ cnt,
                                            float* __restrict__ accum) {
    const int i = blockIdx.x * BLK + threadIdx.x;
    float s_main = 0.f, n_main = 0.f, s_bnd = 0.f, n_bnd = 0.f;
    if (i < N_PTS) {
        int s = seg[i];
        bool valid = (s != -1);
        const float* row = logits + (size_t)i * NCLS;
        float m = -3.0e38f;
#pragma unroll
        for (int c = 0; c < NCLS; c++) m = fmaxf(m, row[c]);
        float se = 0.f;
#pragma unroll
        for (int c = 0; c < NCLS; c++) se += __expf(row[c] - m);
        int tgt = min(max(s, 0), NCLS - 1);
        float logp = row[tgt] - m - __logf(se);
        // cnt includes self exactly once
        bool bnd = valid && ((cnt[i] - 1) < KNN);
        if (valid) { s_main = logp; n_main = 1.f; }
        if (bnd)   { s_bnd  = logp; n_bnd  = 1.f; }
    }
    s_main = waveReduceSum(s_main);
    n_main = waveReduceSum(n_main);
    s_bnd  = waveReduceSum(s_bnd);
    n_bnd  = waveReduceSum(n_bnd);
    if ((threadIdx.x & 63) == 0) {
        atomicAdd(&accum[0], s_main);
        atomicAdd(&accum[1], n_main);
        atomicAdd(&accum[2], s_bnd);
        atomicAdd(&accum[3], n_bnd);
    }
}

__global__ void k_final(const float* __restrict__ accum, float* __restrict__ out) {
    float s_main = accum[0], c_main = accum[1];
    float s_bnd = accum[2], c_bnd = accum[3];
    float main_loss = (c_main > 0.f) ? (-s_main / fmaxf(c_main, 1.f)) : 0.f;
    float bnd_loss  = (c_bnd  > 0.f) ? (-s_bnd  / fmaxf(c_bnd,  1.f)) : 0.f;
    out[0] = main_loss + BND_W * bnd_loss;
}

extern "C" void kernel_launch(void* const* d_in, const int* in_sizes, int n_in,
                              void* d_out, int out_size, void* d_ws, size_t ws_size,
                              hipStream_t stream) {
    const float* coord  = (const float*)d_in[0];
    const float* logits = (const float*)d_in[1];
    const int*   seg    = (const int*)d_in[2];
    (void)in_sizes; (void)n_in; (void)out_size; (void)ws_size;

    unsigned int* dmin_bits = (unsigned int*)d_ws;                    // N u32
    int*          cnt       = (int*)((char*)d_ws + N_PTS * 4);       // N i32
    float*        accum     = (float*)((char*)d_ws + 2 * N_PTS * 4); // 4 f32

    // init: dmin = 0x7F7F7F7F (3.39e38, acts as +inf; bit pattern monotone for f32>=0)
    hipMemsetAsync(dmin_bits, 0x7F, N_PTS * 4, stream);
    hipMemsetAsync(cnt, 0, N_PTS * 4 + 16, stream);

    dim3 grid(PB, CC);
    k_dmin <<<grid, BLK, 0, stream>>>(coord, seg, dmin_bits);
    k_count<<<grid, BLK, 0, stream>>>(coord, dmin_bits, cnt);
    k_ce   <<<N_PTS / BLK, BLK, 0, stream>>>(logits, seg, cnt, accum);
    k_final<<<1, 1, 0, stream>>>(accum, (float*)d_out);
}

// Round 2
// 95.825 us; speedup vs baseline: 1.3293x; 1.3293x over previous
//
#include <hip/hip_runtime.h>
#include <math.h>

#define N_PTS 16384
#define KNN   16
#define NCLS  20
#define BND_W 1.0f

#define BLK   256            // threads per block
#define CPT   8              // centers per thread
#define CPB   (BLK * CPT)    // centers per block = 2048
#define PB    (N_PTS / CPB)  // point blocks = 8
#define CHUNK 256            // candidates per chunk (== BLK: 1 stage op/thread)
#define CC    (N_PTS / CHUNK) // candidate chunks = 64

// order-preserving float<->uint map (works for negative floats) for atomicMax
__device__ __forceinline__ unsigned enc_f(float f) {
    unsigned b = __float_as_uint(f);
    return (b & 0x80000000u) ? ~b : (b | 0x80000000u);
}
__device__ __forceinline__ float dec_f(unsigned u) {
    unsigned b = (u & 0x80000000u) ? (u ^ 0x80000000u) : ~u;
    return __uint_as_float(b);
}

// staged candidate: (x, y, z, h') with h' = 0.5*|v|^2, label+1 packed in low 5
// mantissa bits. Identical packing in both passes -> bit-exact consistent s.
__device__ __forceinline__ float4 stage_point(const float* __restrict__ coord,
                                              const int* __restrict__ seg, int j) {
    float x = coord[3 * j + 0], y = coord[3 * j + 1], z = coord[3 * j + 2];
    float h = 0.5f * fmaf(x, x, fmaf(y, y, z * z));
    unsigned hb = (__float_as_uint(h) & ~31u) | (unsigned)(seg[j] + 1);
    float4 v;
    v.x = x; v.y = y; v.z = z; v.w = __uint_as_float(hb);
    return v;
}

// score: maximizing s <=> minimizing squared distance (s = c.v - 0.5|v|^2)
// 3 fmaf per pair; -v.w is a free input modifier.
__device__ __forceinline__ float score(float cx, float cy, float cz, float4 v) {
    return fmaf(cx, v.x, fmaf(cy, v.y, fmaf(cz, v.z, -v.w)));
}

__global__ __launch_bounds__(BLK) void k_init(unsigned* __restrict__ smax_enc,
                                              int* __restrict__ cnt,
                                              float* __restrict__ accum) {
    int i = blockIdx.x * BLK + threadIdx.x;
    if (i < N_PTS) {
        smax_enc[i] = enc_f(-3.0e38f);  // "no diff neighbor" -> count all -> not boundary
        cnt[i] = 0;
    }
    if (i < 4) accum[i] = 0.f;
}

// Pass 1: per-center max score over valid, differently-labeled candidates.
__global__ __launch_bounds__(BLK) void k_smax(const float* __restrict__ coord,
                                              const int* __restrict__ seg,
                                              unsigned* __restrict__ smax_enc) {
    __shared__ float4 lds[CHUNK];
    const int tid = threadIdx.x;
    lds[tid] = stage_point(coord, seg, blockIdx.y * CHUNK + tid);
    __syncthreads();

    const int base = blockIdx.x * CPB;
    float cx[CPT], cy[CPT], cz[CPT], smax[CPT];
    int csp1[CPT];
#pragma unroll
    for (int c = 0; c < CPT; c++) {
        int i = base + c * BLK + tid;
        cx[c] = coord[3 * i + 0];
        cy[c] = coord[3 * i + 1];
        cz[c] = coord[3 * i + 2];
        csp1[c] = seg[i] + 1;
        smax[c] = -3.0e38f;
    }

#pragma unroll 4
    for (int t = 0; t < CHUNK; t++) {
        float4 v = lds[t];
        int lab = __float_as_int(v.w) & 31;
        bool lv = (lab != 0);
#pragma unroll
        for (int c = 0; c < CPT; c++) {
            float s = score(cx[c], cy[c], cz[c], v);
            bool diff = lv && (lab != csp1[c]);
            smax[c] = fmaxf(smax[c], diff ? s : -3.0e38f);
        }
    }

#pragma unroll
    for (int c = 0; c < CPT; c++)
        atomicMax(&smax_enc[base + c * BLK + tid], enc_f(smax[c]));
}

// Pass 2: count candidates with s strictly greater than smax (closer than the
// nearest diff point). Self is included exactly once (s_self ~ 0.5|c|^2 > smax).
// The nearest-diff point itself evaluates s == smax -> excluded by strict >.
__global__ __launch_bounds__(BLK) void k_count(const float* __restrict__ coord,
                                               const int* __restrict__ seg,
                                               const unsigned* __restrict__ smax_enc,
                                               int* __restrict__ cnt) {
    __shared__ float4 lds[CHUNK];
    const int tid = threadIdx.x;
    lds[tid] = stage_point(coord, seg, blockIdx.y * CHUNK + tid);
    __syncthreads();

    const int base = blockIdx.x * CPB;
    float cx[CPT], cy[CPT], cz[CPT], thr[CPT];
    int lcnt[CPT];
#pragma unroll
    for (int c = 0; c < CPT; c++) {
        int i = base + c * BLK + tid;
        cx[c] = coord[3 * i + 0];
        cy[c] = coord[3 * i + 1];
        cz[c] = coord[3 * i + 2];
        thr[c] = dec_f(smax_enc[i]);
        lcnt[c] = 0;
    }

#pragma unroll 4
    for (int t = 0; t < CHUNK; t++) {
        float4 v = lds[t];
#pragma unroll
        for (int c = 0; c < CPT; c++) {
            float s = score(cx[c], cy[c], cz[c], v);
            lcnt[c] += (s > thr[c]) ? 1 : 0;
        }
    }

#pragma unroll
    for (int c = 0; c < CPT; c++)
        atomicAdd(&cnt[base + c * BLK + tid], lcnt[c]);
}

__device__ __forceinline__ float waveReduceSum(float v) {
#pragma unroll
    for (int off = 32; off > 0; off >>= 1) v += __shfl_down(v, off, 64);
    return v;
}

// Pass 3: cross-entropy + masked accumulation.
// accum: [0]=sum_main, [1]=cnt_main, [2]=sum_bnd, [3]=cnt_bnd
__global__ __launch_bounds__(BLK) void k_ce(const float* __restrict__ logits,
                                            const int* __restrict__ seg,
                                            const int* __restrict__ cnt,
                                            float* __restrict__ accum) {
    const int i = blockIdx.x * BLK + threadIdx.x;
    float s_main = 0.f, n_main = 0.f, s_bnd = 0.f, n_bnd = 0.f;
    if (i < N_PTS) {
        int s = seg[i];
        bool valid = (s != -1);
        const float* row = logits + (size_t)i * NCLS;
        float m = -3.0e38f;
#pragma unroll
        for (int c = 0; c < NCLS; c++) m = fmaxf(m, row[c]);
        float se = 0.f;
#pragma unroll
        for (int c = 0; c < NCLS; c++) se += __expf(row[c] - m);
        int tgt = min(max(s, 0), NCLS - 1);
        float logp = row[tgt] - m - __logf(se);
        // cnt includes self exactly once; boundary iff rank of nearest diff < K
        bool bnd = valid && ((cnt[i] - 1) < KNN);
        if (valid) { s_main = logp; n_main = 1.f; }
        if (bnd)   { s_bnd  = logp; n_bnd  = 1.f; }
    }
    s_main = waveReduceSum(s_main);
    n_main = waveReduceSum(n_main);
    s_bnd  = waveReduceSum(s_bnd);
    n_bnd  = waveReduceSum(n_bnd);
    if ((threadIdx.x & 63) == 0) {
        atomicAdd(&accum[0], s_main);
        atomicAdd(&accum[1], n_main);
        atomicAdd(&accum[2], s_bnd);
        atomicAdd(&accum[3], n_bnd);
    }
}

__global__ void k_final(const float* __restrict__ accum, float* __restrict__ out) {
    float s_main = accum[0], c_main = accum[1];
    float s_bnd = accum[2], c_bnd = accum[3];
    float main_loss = (c_main > 0.f) ? (-s_main / fmaxf(c_main, 1.f)) : 0.f;
    float bnd_loss  = (c_bnd  > 0.f) ? (-s_bnd  / fmaxf(c_bnd,  1.f)) : 0.f;
    out[0] = main_loss + BND_W * bnd_loss;
}

extern "C" void kernel_launch(void* const* d_in, const int* in_sizes, int n_in,
                              void* d_out, int out_size, void* d_ws, size_t ws_size,
                              hipStream_t stream) {
    const float* coord  = (const float*)d_in[0];
    const float* logits = (const float*)d_in[1];
    const int*   seg    = (const int*)d_in[2];
    (void)in_sizes; (void)n_in; (void)out_size; (void)ws_size;

    unsigned* smax_enc = (unsigned*)d_ws;                          // N u32
    int*      cnt      = (int*)((char*)d_ws + N_PTS * 4);          // N i32
    float*    accum    = (float*)((char*)d_ws + 2 * N_PTS * 4);    // 4 f32

    dim3 grid(PB, CC);
    k_init <<<N_PTS / BLK, BLK, 0, stream>>>(smax_enc, cnt, accum);
    k_smax <<<grid, BLK, 0, stream>>>(coord, seg, smax_enc);
    k_count<<<grid, BLK, 0, stream>>>(coord, seg, smax_enc, cnt);
    k_ce   <<<N_PTS / BLK, BLK, 0, stream>>>(logits, seg, cnt, accum);
    k_final<<<1, 1, 0, stream>>>(accum, (float*)d_out);
}

// Round 3
// 67.015 us; speedup vs baseline: 1.9008x; 1.4299x over previous
//
#include <hip/hip_runtime.h>
#include <hip/hip_bf16.h>
#include <math.h>

#define N_PTS 16384
#define KNN   16
#define NCLS  20
#define BND_W 1.0f
#define BIGM  1024.0f

#define THREADS 512
#define WAVES   8
#define ROWS_PER_WAVE  32
#define ROWS_PER_BLOCK 256                 // 8 waves * 32 rows
#define ROW_BLOCKS     (N_PTS / ROWS_PER_BLOCK)   // 64
#define CSPLIT         8
#define CANDS_PER_BLOCK (N_PTS / CSPLIT)   // 2048
#define CHUNK          1024
#define NCHUNK         (CANDS_PER_BLOCK / CHUNK)  // 2

typedef short  short8 __attribute__((ext_vector_type(8)));
typedef float  f32x4  __attribute__((ext_vector_type(4)));

// ---- float <-> order-preserving uint (atomicMax over possibly-negative f32) ----
__device__ __forceinline__ unsigned enc_f(float f) {
    unsigned b = __float_as_uint(f);
    return (b & 0x80000000u) ? ~b : (b | 0x80000000u);
}
__device__ __forceinline__ float dec_f(unsigned u) {
    unsigned b = (u & 0x80000000u) ? (u ^ 0x80000000u) : ~u;
    return __uint_as_float(b);
}

// ---- bf16 helpers (RNE) ----
__device__ __forceinline__ unsigned short f2bf(float x) {
    union { __hip_bfloat16 h; unsigned short u; } cv;
    cv.h = __float2bfloat16(x);
    return cv.u;
}
__device__ __forceinline__ float bf2f(unsigned short b) {
    union { __hip_bfloat16 h; unsigned short u; } cv;
    cv.u = b;
    return __bfloat162float(cv.h);
}

// Candidate encoding (B operand), 32 bf16 slots:
//  coords: (xh,xh,xl)(yh,yh,yl)(zh,zh,zl) slots 0..8
//  slots 9,10: -h_hi, -h_lo  with h = 0.5*|v|^2
//  slots 11..30: one-hot(label) = 1.0 ; slot 31: 1.0 iff label==-1
// NOTE: only static indexing (rule: runtime-indexed stack arrays go to scratch)
__device__ __forceinline__ void build_b(const float* __restrict__ coord,
                                        const int* __restrict__ seg, int j,
                                        unsigned short* out) {
    float x = coord[3 * j], y = coord[3 * j + 1], z = coord[3 * j + 2];
    int lab = seg[j];
    unsigned short xh = f2bf(x), yh = f2bf(y), zh = f2bf(z);
    unsigned short xl = f2bf(x - bf2f(xh));
    unsigned short yl = f2bf(y - bf2f(yh));
    unsigned short zl = f2bf(z - bf2f(zh));
    float h = 0.5f * fmaf(x, x, fmaf(y, y, z * z));
    unsigned short hh = f2bf(h);
    unsigned short hl = f2bf(h - bf2f(hh));
    out[0] = xh; out[1] = xh; out[2] = xl;
    out[3] = yh; out[4] = yh; out[5] = yl;
    out[6] = zh; out[7] = zh; out[8] = zl;
    out[9]  = hh ^ 0x8000u;   // -h_hi
    out[10] = hl ^ 0x8000u;   // -h_lo
#pragma unroll
    for (int s = 0; s < NCLS; s++) out[11 + s] = (lab == s) ? 0x3F80u : 0u;  // 1.0
    out[31] = (lab < 0) ? 0x3F80u : 0u;
}

// Center encoding (A operand): coords (xh,xl,xh)... ; slots 9,10 = 1.0;
// pass1: -BIG one-hot at own class + slot31 = -BIG; pass2: label slots all 0.
template<bool PASS1>
__device__ __forceinline__ void build_a(const float* __restrict__ coord,
                                        const int* __restrict__ seg, int i,
                                        unsigned short* out) {
    float x = coord[3 * i], y = coord[3 * i + 1], z = coord[3 * i + 2];
    int lab = seg[i];
    unsigned short xh = f2bf(x), yh = f2bf(y), zh = f2bf(z);
    unsigned short xl = f2bf(x - bf2f(xh));
    unsigned short yl = f2bf(y - bf2f(yh));
    unsigned short zl = f2bf(z - bf2f(zh));
    out[0] = xh; out[1] = xl; out[2] = xh;
    out[3] = yh; out[4] = yl; out[5] = yh;
    out[6] = zh; out[7] = zl; out[8] = zh;
    out[9] = 0x3F80u; out[10] = 0x3F80u;     // 1.0 (picks up -h_hi, -h_lo)
    const unsigned short nb = 0xC480u;       // bf16(-1024.0)
#pragma unroll
    for (int s = 0; s < NCLS; s++) out[11 + s] = (PASS1 && lab == s) ? nb : 0u;
    out[31] = PASS1 ? nb : 0u;
}

__global__ __launch_bounds__(256) void k_init(unsigned* __restrict__ smax_enc,
                                              int* __restrict__ cnt,
                                              float* __restrict__ accum) {
    int i = blockIdx.x * 256 + threadIdx.x;
    if (i < N_PTS) {
        smax_enc[i] = enc_f(-3.0e38f);
        cnt[i] = 0;
    }
    if (i < 4) accum[i] = 0.f;
}

// One kernel for both passes over the score matrix S[i][j] = c_i . b_j
// (MFMA 16x16x32 bf16; rows=centers from A, cols=candidates from B).
template<bool PASS1>
__global__ __launch_bounds__(THREADS) void k_pass(const float* __restrict__ coord,
                                                  const int* __restrict__ seg,
                                                  unsigned* __restrict__ smax_enc,
                                                  int* __restrict__ cnt) {
    __shared__ unsigned short smem[CHUNK * 32];  // 64 KB; reused: A-table then B-chunks
    const int tid  = threadIdx.x;
    const int lane = tid & 63, wave = tid >> 6;
    const int l15  = lane & 15, l4 = lane >> 4;
    const int rb   = blockIdx.x * ROWS_PER_BLOCK;
    const int cb   = blockIdx.y * CANDS_PER_BLOCK;

    // ---- build center encodings in LDS, load A fragments ----
    if (tid < ROWS_PER_BLOCK) build_a<PASS1>(coord, seg, rb + tid, &smem[tid * 32]);
    __syncthreads();
    short8 afrag0, afrag1;
    {
        // A[m][k]: lane holds row m=l&15, k-block = l>>4 (8 bf16)
        const short8* ap = (const short8*)smem;
        int r0 = wave * ROWS_PER_WAVE + l15;
        afrag0 = ap[r0 * 4 + l4];
        afrag1 = ap[(r0 + 16) * 4 + l4];
    }
    __syncthreads();

    // D layout: col = lane&15 (candidate), row = (lane>>4)*4 + reg (center)
    const int row0 = rb + wave * ROWS_PER_WAVE + l4 * 4;

    f32x4 rmax0, rmax1;
    int   cv0[4], cv1[4];
    float thr0[4], thr1[4];
    if (PASS1) {
#pragma unroll
        for (int r = 0; r < 4; r++) { rmax0[r] = -3.0e38f; rmax1[r] = -3.0e38f; }
    } else {
#pragma unroll
        for (int r = 0; r < 4; r++) {
            thr0[r] = dec_f(smax_enc[row0 + r]);
            thr1[r] = dec_f(smax_enc[row0 + 16 + r]);
            cv0[r] = 0; cv1[r] = 0;
        }
    }

    const short8* bp = (const short8*)smem;
    // swizzled B-frag index (short8 units); c0*4 folds into ds_read immediates
    const int bidx = l15 * 4 + (l4 ^ ((l15 >> 1) & 3));
    const f32x4 zero = {0.f, 0.f, 0.f, 0.f};

    for (int cc = 0; cc < NCHUNK; cc++) {
        // ---- stage 1024 candidate encodings (XOR-swizzled, 2-way = free) ----
#pragma unroll
        for (int u = 0; u < 2; u++) {
            int c = tid + u * THREADS;
            __attribute__((aligned(16))) unsigned short be[32];
            build_b(coord, seg, cb + cc * CHUNK + c, be);
            short8* wp = (short8*)smem;
            int swz = (c >> 1) & 3;
#pragma unroll
            for (int kb = 0; kb < 4; kb++)
                wp[c * 4 + (kb ^ swz)] = ((const short8*)be)[kb];
        }
        __syncthreads();

        // ---- sweep: 1 ds_read_b128 + 2 MFMA + 8 VALU per 16 candidates ----
#pragma unroll 8
        for (int c0 = 0; c0 < CHUNK; c0 += 16) {
            short8 bfrag = bp[bidx + c0 * 4];
            f32x4 d0 = __builtin_amdgcn_mfma_f32_16x16x32_bf16(afrag0, bfrag, zero, 0, 0, 0);
            f32x4 d1 = __builtin_amdgcn_mfma_f32_16x16x32_bf16(afrag1, bfrag, zero, 0, 0, 0);
            if (PASS1) {
#pragma unroll
                for (int r = 0; r < 4; r++) {
                    rmax0[r] = fmaxf(rmax0[r], d0[r]);
                    rmax1[r] = fmaxf(rmax1[r], d1[r]);
                }
            } else {
#pragma unroll
                for (int r = 0; r < 4; r++) {
                    cv0[r] += (d0[r] > thr0[r]) ? 1 : 0;
                    cv1[r] += (d1[r] > thr1[r]) ? 1 : 0;
                }
            }
        }
        __syncthreads();
    }

    // ---- reduce across the 16 column-lanes, then merge across cand-splits ----
    if (PASS1) {
#pragma unroll
        for (int m = 1; m < 16; m <<= 1) {
#pragma unroll
            for (int r = 0; r < 4; r++) {
                rmax0[r] = fmaxf(rmax0[r], __shfl_xor(rmax0[r], m, 64));
                rmax1[r] = fmaxf(rmax1[r], __shfl_xor(rmax1[r], m, 64));
            }
        }
        if (l15 == 0) {
#pragma unroll
            for (int r = 0; r < 4; r++) {
                atomicMax(&smax_enc[row0 + r],      enc_f(rmax0[r]));
                atomicMax(&smax_enc[row0 + 16 + r], enc_f(rmax1[r]));
            }
        }
    } else {
#pragma unroll
        for (int m = 1; m < 16; m <<= 1) {
#pragma unroll
            for (int r = 0; r < 4; r++) {
                cv0[r] += __shfl_xor(cv0[r], m, 64);
                cv1[r] += __shfl_xor(cv1[r], m, 64);
            }
        }
        if (l15 == 0) {
#pragma unroll
            for (int r = 0; r < 4; r++) {
                atomicAdd(&cnt[row0 + r],      cv0[r]);
                atomicAdd(&cnt[row0 + 16 + r], cv1[r]);
            }
        }
    }
}

__device__ __forceinline__ float waveReduceSum(float v) {
#pragma unroll
    for (int off = 32; off > 0; off >>= 1) v += __shfl_down(v, off, 64);
    return v;
}

// accum: [0]=sum_main, [1]=cnt_main, [2]=sum_bnd, [3]=cnt_bnd
__global__ __launch_bounds__(256) void k_ce(const float* __restrict__ logits,
                                            const int* __restrict__ seg,
                                            const int* __restrict__ cnt,
                                            float* __restrict__ accum) {
    const int i = blockIdx.x * 256 + threadIdx.x;
    float s_main = 0.f, n_main = 0.f, s_bnd = 0.f, n_bnd = 0.f;
    if (i < N_PTS) {
        int s = seg[i];
        bool valid = (s != -1);
        const float* row = logits + (size_t)i * NCLS;
        float m = -3.0e38f;
#pragma unroll
        for (int c = 0; c < NCLS; c++) m = fmaxf(m, row[c]);
        float se = 0.f;
#pragma unroll
        for (int c = 0; c < NCLS; c++) se += __expf(row[c] - m);
        int tgt = min(max(s, 0), NCLS - 1);
        float logp = row[tgt] - m - __logf(se);
        // cnt includes self exactly once; boundary iff rank of nearest diff < K
        bool bnd = valid && ((cnt[i] - 1) < KNN);
        if (valid) { s_main = logp; n_main = 1.f; }
        if (bnd)   { s_bnd  = logp; n_bnd  = 1.f; }
    }
    s_main = waveReduceSum(s_main);
    n_main = waveReduceSum(n_main);
    s_bnd  = waveReduceSum(s_bnd);
    n_bnd  = waveReduceSum(n_bnd);
    if ((threadIdx.x & 63) == 0) {
        atomicAdd(&accum[0], s_main);
        atomicAdd(&accum[1], n_main);
        atomicAdd(&accum[2], s_bnd);
        atomicAdd(&accum[3], n_bnd);
    }
}

__global__ void k_final(const float* __restrict__ accum, float* __restrict__ out) {
    float s_main = accum[0], c_main = accum[1];
    float s_bnd = accum[2], c_bnd = accum[3];
    float main_loss = (c_main > 0.f) ? (-s_main / fmaxf(c_main, 1.f)) : 0.f;
    float bnd_loss  = (c_bnd  > 0.f) ? (-s_bnd  / fmaxf(c_bnd,  1.f)) : 0.f;
    out[0] = main_loss + BND_W * bnd_loss;
}

extern "C" void kernel_launch(void* const* d_in, const int* in_sizes, int n_in,
                              void* d_out, int out_size, void* d_ws, size_t ws_size,
                              hipStream_t stream) {
    const float* coord  = (const float*)d_in[0];
    const float* logits = (const float*)d_in[1];
    const int*   seg    = (const int*)d_in[2];
    (void)in_sizes; (void)n_in; (void)out_size; (void)ws_size;

    unsigned* smax_enc = (unsigned*)d_ws;                          // N u32
    int*      cnt      = (int*)((char*)d_ws + N_PTS * 4);          // N i32
    float*    accum    = (float*)((char*)d_ws + 2 * N_PTS * 4);    // 4 f32

    dim3 grid(ROW_BLOCKS, CSPLIT);
    k_init       <<<N_PTS / 256, 256, 0, stream>>>(smax_enc, cnt, accum);
    k_pass<true> <<<grid, THREADS, 0, stream>>>(coord, seg, smax_enc, cnt);
    k_pass<false><<<grid, THREADS, 0, stream>>>(coord, seg, smax_enc, cnt);
    k_ce         <<<N_PTS / 256, 256, 0, stream>>>(logits, seg, cnt, accum);
    k_final      <<<1, 1, 0, stream>>>(accum, (float*)d_out);
}